// Round 18
// baseline (198.380 us; speedup 1.0000x reference)
//
#include <hip/hip_runtime.h>
#include <hip/hip_bf16.h>
#include <math.h>

#define LN_EPS 1e-5f

typedef __attribute__((ext_vector_type(4))) float f4_t;
typedef __attribute__((ext_vector_type(8))) short bf8_t;

__device__ __forceinline__ unsigned short f2bf(float x) {
    unsigned u = __builtin_bit_cast(unsigned, x);
    unsigned r = (u + 0x7FFFu + ((u >> 16) & 1u)) >> 16;
    return (unsigned short)r;
}
__device__ __forceinline__ float bf2f(unsigned short u) {
    return __builtin_bit_cast(float, ((unsigned)u) << 16);
}
// exact GELU: 0.5x(1+erf(x/sqrt2)), erf via A&S 7.1.26 (|eps|<=1.5e-7)
__device__ __forceinline__ float gelu_f(float x) {
    float z = x * 0.70710678f;
    float az = fabsf(z);
    float t = __builtin_amdgcn_rcpf(1.f + 0.3275911f * az);
    float y = t * (0.254829592f + t * (-0.284496736f + t * (1.421413741f +
              t * (-1.453152027f + t * 1.061405429f))));
    float e = 1.f - y * __expf(-az * az);
    return 0.5f * x * (1.f + copysignf(e, x));
}

// LDS-ordering barrier that does not drain vmcnt (global prefetches survive).
__device__ __forceinline__ void light_barrier() {
    asm volatile("s_waitcnt lgkmcnt(0)" ::: "memory");
    __builtin_amdgcn_s_barrier();
}

// ---------------- kernel 1: pool (blocks 0..2047) + weight cvt (2048..2303) ---
__global__ __launch_bounds__(256) void pool_cvt_kernel(
    const float* __restrict__ feature, float* __restrict__ fs,
    const float* __restrict__ W1, const float* __restrict__ W2,
    bf8_t* __restrict__ W1f, bf8_t* __restrict__ W2f) {
    __shared__ float ftile[6400];
    int tid = threadIdx.x;
    if (blockIdx.x >= 2048) {
        int gid = (blockIdx.x - 2048) * 256 + tid;   // 0..65535
        union { bf8_t v; unsigned short u[8]; } pk;
        if (gid < 32768) {
            int lane = gid & 63;
            int f = (gid >> 9) * 16 + (lane & 15);
            int k = ((gid >> 6) & 7) * 32 + (lane >> 4) * 8;
            const float* src = W1 + (size_t)f * 256 + k;
#pragma unroll
            for (int e = 0; e < 8; ++e) pk.u[e] = f2bf(src[e]);
            W1f[gid] = pk.v;
        } else {
            int g = gid - 32768;
            int lane = g & 63;
            int c = (g >> 11) * 16 + (lane & 15);
            int k = ((g >> 6) & 31) * 32 + (lane >> 4) * 8;
            const float* src = W2 + (size_t)c * 1024 + k;
#pragma unroll
            for (int e = 0; e < 8; ++e) pk.u[e] = f2bf(src[e]);
            W2f[g] = pk.v;
        }
        return;
    }
    int b = blockIdx.x;            // n*256 + c
    int n = b >> 8, c = b & 255;
    const float4* src = reinterpret_cast<const float4*>(feature + ((size_t)b) * 6400);
#pragma unroll
    for (int i = 0; i < 6; ++i) {
        int idx = i * 256 + tid;                 // 0..1535
        float4 v = src[idx];
        *reinterpret_cast<float4*>(&ftile[idx * 4]) = v;
    }
    if (tid < 64) {
        int idx = 1536 + tid;
        float4 v = src[idx];
        *reinterpret_cast<float4*>(&ftile[idx * 4]) = v;
    }
    __syncthreads();
    float* dst = fs + (size_t)n * 400 * 256 + c;
#pragma unroll
    for (int pass = 0; pass < 2; ++pass) {
        int k = pass * 256 + tid;
        if (k < 400) {
            int h = k / 20, w = k % 20;
            const float* p = &ftile[(h * 4) * 80 + w * 4];
            float s = 0.f;
#pragma unroll
            for (int dh = 0; dh < 4; ++dh)
                s += p[dh * 80 + 0] + p[dh * 80 + 1] + p[dh * 80 + 2] + p[dh * 80 + 3];
            dst[(size_t)k * 256] = s;
        }
    }
}

// ---------------- kernel 2: r[n][i][c] = sum_k weight[n][i][k] * fs[n][k][c] ---
// 8 rows/block, 64-k LDS chunks, tail-guarded (R17 proven).
__global__ __launch_bounds__(256) void att_kernel(const float* __restrict__ wgt,
                                                  const float* __restrict__ fs,
                                                  float* __restrict__ r) {
    __shared__ float fsl[64][256];   // 64 KB
    __shared__ float wl[8][64];      // 2 KB
    int b = blockIdx.x;
    int n = b / 50, i0 = (b % 50) * 8;
    int tid = threadIdx.x;
    const float* wbase = wgt + (size_t)n * 400 * 400;
    const float* fsbase = fs + (size_t)n * 400 * 256;
    float acc[8] = {0.f, 0.f, 0.f, 0.f, 0.f, 0.f, 0.f, 0.f};
    for (int k0 = 0; k0 < 400; k0 += 64) {
        int kn = (k0 + 64 <= 400) ? 64 : (400 - k0);
        for (int kk = 0; kk < kn; ++kk)
            fsl[kk][tid] = fsbase[(size_t)(k0 + kk) * 256 + tid];
#pragma unroll
        for (int pass = 0; pass < 2; ++pass) {
            int idx = pass * 256 + tid;          // 0..511
            int ii = idx >> 6, kk = idx & 63;
            if (kk < kn)
                wl[ii][kk] = wbase[(size_t)(i0 + ii) * 400 + k0 + kk];
        }
        __syncthreads();
        for (int kk = 0; kk < kn; ++kk) {
            float f = fsl[kk][tid];
#pragma unroll
            for (int ii = 0; ii < 8; ++ii) acc[ii] += wl[ii][kk] * f;
        }
        __syncthreads();
    }
#pragma unroll
    for (int ii = 0; ii < 8; ++ii)
        r[((size_t)n * 400 + i0 + ii) * 256 + tid] = acc[ii];
}

// ---------------- kernel 3: fused residual+att + LN1 + MLP(GELU) + LN2 ---------
// R15/R17 structure re-divided across 8 WAVES (512 thr), 64 tokens as two
// 32-halves sharing B-frags, 800 blocks. LDS 53.76 KB -> 3 blocks/CU = 24
// waves/CU (2x R17's 12). Wave q: G1 f-tile fc*8+q, G2 c-tiles {2q,2q+1}.
__global__ __launch_bounds__(512, 2) void main_kernel(
    const float* __restrict__ feat, const float* __restrict__ r,
    const float* __restrict__ ln1g, const float* __restrict__ ln1b,
    const bf8_t* __restrict__ W1f, const float* __restrict__ b1,
    const bf8_t* __restrict__ W2f, const float* __restrict__ b2,
    const float* __restrict__ ln2g, const float* __restrict__ ln2b,
    float* __restrict__ out) {
    __shared__ unsigned short xt[64 * 256];      // [t][c] swizzled, 32 KB
    __shared__ unsigned short ht[2][32 * 128];   // per-half [t32][f] swizzled, 2x8 KB
    __shared__ float psum[8][64], psq[8][64];    // 4 KB
    __shared__ float stat[2][64];

    int bid = blockIdx.x;
    int n = bid / 100;
    int p0 = (bid % 100) * 64;
    int tid = threadIdx.x;
    int lane = tid & 63;
    int q = tid >> 6;                     // wave id 0..7
    int t = lane;                         // token row (phase 1)
    int p = p0 + t;
    int iatt = ((p / 80) >> 2) * 20 + ((p % 80) >> 2);

    // ---- phase 1 pass 1: x = residual + att -> raw bf16 into xt, stats in regs.
    // Thread covers 32 channels (group q) of token t.
    const float* fbase = feat + ((size_t)(n * 256 + q * 32)) * 6400 + p;
    const float* rrow = r + ((size_t)(n * 400 + iatt)) * 256 + q * 32;
    float s1 = 0.f, s2 = 0.f;
#pragma unroll
    for (int jj = 0; jj < 4; ++jj) {
        union { bf8_t v; unsigned short u[8]; } pk;
#pragma unroll
        for (int e = 0; e < 8; ++e) {
            int j = jj * 8 + e;
            float v = fbase[(size_t)j * 6400] + rrow[j];
            s1 += v;
            s2 += v * v;
            pk.u[e] = f2bf(v);
        }
        int byte = t * 512 + ((q * 64 + jj * 16) ^ ((t & 7) << 4));
        *reinterpret_cast<bf8_t*>(reinterpret_cast<char*>(xt) + byte) = pk.v;
    }
    psum[q][t] = s1;
    psq[q][t] = s2;
    light_barrier();
    if (tid < 64) {
        float a = 0.f, b = 0.f;
#pragma unroll
        for (int gg = 0; gg < 8; ++gg) { a += psum[gg][tid]; b += psq[gg][tid]; }
        float mu = a * (1.f / 256.f);
        float var = b * (1.f / 256.f) - mu * mu;
        stat[0][tid] = mu;
        stat[1][tid] = rsqrtf(var + LN_EPS);
    }
    light_barrier();
    // ---- phase 1 pass 2: normalize xt in place.
    float mu = stat[0][t], rs = stat[1][t];
#pragma unroll
    for (int jj = 0; jj < 4; ++jj) {
        int byte = t * 512 + ((q * 64 + jj * 16) ^ ((t & 7) << 4));
        union { bf8_t v; unsigned short u[8]; } pk;
        pk.v = *reinterpret_cast<const bf8_t*>(reinterpret_cast<const char*>(xt) + byte);
#pragma unroll
        for (int e = 0; e < 8; ++e) {
            int c = q * 32 + jj * 8 + e;
            float v = bf2f(pk.u[e]);
            pk.u[e] = f2bf((v - mu) * rs * ln1g[c] + ln1b[c]);
        }
        *reinterpret_cast<bf8_t*>(reinterpret_cast<char*>(xt) + byte) = pk.v;
    }
    light_barrier();

    // ---- MFMA phase ----
    int lm = lane & 15, lk = lane >> 4;
    const char* xtb = reinterpret_cast<const char*>(xt);

    f4_t oacc[8];   // [hh*4 + m*2 + cl]
#pragma unroll
    for (int i = 0; i < 8; ++i) oacc[i] = (f4_t){0.f, 0.f, 0.f, 0.f};

    // prologue: prefetch fc=0's W1 frags (f-tile q)
    bf8_t bfr0[8];
    {
        const bf8_t* w1p = W1f + ((size_t)q * 8) * 64 + lane;
#pragma unroll
        for (int kb = 0; kb < 8; ++kb) bfr0[kb] = w1p[kb * 64];
    }

    for (int fc = 0; fc < 8; ++fc) {
        // GEMM1: wave q owns f-tile fc*8+q; both halves share bfr0.
        f4_t hacc[4];   // [hh*2+m]
#pragma unroll
        for (int i = 0; i < 4; ++i) hacc[i] = (f4_t){0.f, 0.f, 0.f, 0.f};
#pragma unroll
        for (int kb = 0; kb < 8; ++kb) {
#pragma unroll
            for (int hh = 0; hh < 2; ++hh) {
#pragma unroll
                for (int m = 0; m < 2; ++m) {
                    int row = hh * 32 + m * 16 + lm;
                    bf8_t a = *reinterpret_cast<const bf8_t*>(
                        xtb + row * 512 + ((kb * 64 + lk * 16) ^ ((row & 7) << 4)));
                    hacc[hh * 2 + m] = __builtin_amdgcn_mfma_f32_16x16x32_bf16(a, bfr0[kb], hacc[hh * 2 + m], 0, 0, 0);
                }
            }
        }
        // issue W2 B-frags (c-tiles {2q,2q+1}); latency hides under GELU
        const bf8_t* w2pA = W2f + ((size_t)(2 * q) * 32 + fc * 4) * 64 + lane;
        const bf8_t* w2pB = W2f + ((size_t)(2 * q + 1) * 32 + fc * 4) * 64 + lane;
        bf8_t b2r[8];
#pragma unroll
        for (int kb = 0; kb < 4; ++kb) {
            b2r[kb * 2 + 0] = w2pA[kb * 64];
            b2r[kb * 2 + 1] = w2pB[kb * 64];
        }
        // bias + exact GELU -> ht[0], ht[1] (wave q owns cols q*16..q*16+15)
        {
            int fl = q * 16 + lm;
            float bias = b1[fc * 128 + fl];
#pragma unroll
            for (int hh = 0; hh < 2; ++hh) {
                char* htc = reinterpret_cast<char*>(ht[hh]);
#pragma unroll
                for (int m = 0; m < 2; ++m) {
#pragma unroll
                    for (int j = 0; j < 4; ++j) {
                        int row = m * 16 + lk * 4 + j;   // half-local 0..31
                        float gv = gelu_f(hacc[hh * 2 + m][j] + bias);
                        *reinterpret_cast<unsigned short*>(
                            htc + row * 256 + ((fl * 2) ^ ((row & 7) << 4))) = f2bf(gv);
                    }
                }
            }
        }
        light_barrier();   // both ht buffers written
        // prefetch NEXT fc's W1 frags (hide under G2 MFMAs)
        if (fc < 7) {
            const bf8_t* w1n = W1f + ((size_t)((fc + 1) * 8 + q) * 8) * 64 + lane;
#pragma unroll
            for (int kb = 0; kb < 8; ++kb) bfr0[kb] = w1n[kb * 64];
        }
        // GEMM2 both halves; B-frags shared across halves
#pragma unroll
        for (int hh = 0; hh < 2; ++hh) {
            const char* htc = reinterpret_cast<const char*>(ht[hh]);
#pragma unroll
            for (int kb = 0; kb < 4; ++kb) {
#pragma unroll
                for (int m = 0; m < 2; ++m) {
                    int row = m * 16 + lm;
                    bf8_t a = *reinterpret_cast<const bf8_t*>(
                        htc + row * 256 + ((kb * 64 + lk * 16) ^ ((row & 7) << 4)));
                    oacc[hh * 4 + m * 2 + 0] = __builtin_amdgcn_mfma_f32_16x16x32_bf16(a, b2r[kb * 2 + 0], oacc[hh * 4 + m * 2 + 0], 0, 0, 0);
                    oacc[hh * 4 + m * 2 + 1] = __builtin_amdgcn_mfma_f32_16x16x32_bf16(a, b2r[kb * 2 + 1], oacc[hh * 4 + m * 2 + 1], 0, 0, 0);
                }
            }
        }
        light_barrier();   // all ht reads done before next fc's GELU writes
    }

    // ---- epilogue: + b2 + residual2, LN2, store. Wave q owns c (2q..2q+1)*16.
    float b2l[2];
#pragma unroll
    for (int cl = 0; cl < 2; ++cl) b2l[cl] = b2[(2 * q + cl) * 16 + lm];
#pragma unroll
    for (int hh = 0; hh < 2; ++hh) {
#pragma unroll
        for (int m = 0; m < 2; ++m) {
#pragma unroll
            for (int j = 0; j < 4; ++j) {
                int row = hh * 32 + m * 16 + lk * 4 + j;
                float s = 0.f, ss = 0.f;
#pragma unroll
                for (int cl = 0; cl < 2; ++cl) {
                    int c = (2 * q + cl) * 16 + lm;
                    float res = bf2f(*reinterpret_cast<const unsigned short*>(
                        xtb + row * 512 + ((c * 2) ^ ((row & 7) << 4))));
                    float v = oacc[hh * 4 + m * 2 + cl][j] + b2l[cl] + res;
                    oacc[hh * 4 + m * 2 + cl][j] = v;
                    s += v;
                    ss += v * v;
                }
#pragma unroll
                for (int d = 1; d < 16; d <<= 1) {
                    s += __shfl_xor(s, d, 64);
                    ss += __shfl_xor(ss, d, 64);
                }
                if (lm == 0) { psum[q][row] = s; psq[q][row] = ss; }
            }
        }
    }
    light_barrier();
    if (tid < 64) {
        float a = 0.f, b = 0.f;
#pragma unroll
        for (int gg = 0; gg < 8; ++gg) { a += psum[gg][tid]; b += psq[gg][tid]; }
        float mu2 = a * (1.f / 256.f);
        float var = b * (1.f / 256.f) - mu2 * mu2;
        stat[0][tid] = mu2;
        stat[1][tid] = rsqrtf(var + LN_EPS);
    }
    light_barrier();
    float g2[2], be2[2];
#pragma unroll
    for (int cl = 0; cl < 2; ++cl) {
        int c = (2 * q + cl) * 16 + lm;
        g2[cl] = ln2g[c];
        be2[cl] = ln2b[c];
    }
    float* obase = out + ((size_t)(n * 6400 + p0)) * 256;
#pragma unroll
    for (int hh = 0; hh < 2; ++hh) {
#pragma unroll
        for (int m = 0; m < 2; ++m) {
#pragma unroll
            for (int j = 0; j < 4; ++j) {
                int row = hh * 32 + m * 16 + lk * 4 + j;
                float mu2 = stat[0][row], r2 = stat[1][row];
#pragma unroll
                for (int cl = 0; cl < 2; ++cl) {
                    int c = (2 * q + cl) * 16 + lm;
                    obase[(size_t)row * 256 + c] =
                        (oacc[hh * 4 + m * 2 + cl][j] - mu2) * r2 * g2[cl] + be2[cl];
                }
            }
        }
    }
}

extern "C" void kernel_launch(void* const* d_in, const int* in_sizes, int n_in,
                              void* d_out, int out_size, void* d_ws, size_t ws_size,
                              hipStream_t stream) {
    const float* weight = (const float*)d_in[0];   // [8,400,400]
    const float* feature = (const float*)d_in[1];  // [8,256,80,80]
    const float* ln1g = (const float*)d_in[2];
    const float* ln1b = (const float*)d_in[3];
    const float* W1 = (const float*)d_in[4];       // [1024,256]
    const float* b1 = (const float*)d_in[5];
    const float* W2 = (const float*)d_in[6];       // [256,1024]
    const float* b2 = (const float*)d_in[7];
    const float* ln2g = (const float*)d_in[8];
    const float* ln2b = (const float*)d_in[9];
    float* outp = (float*)d_out;

    float* fs = (float*)d_ws;                         // 819200 f32
    float* rbuf = fs + 819200;                        // 819200 f32
    bf8_t* W1f = (bf8_t*)(rbuf + 819200);             // 32768 frags (512 KB)
    bf8_t* W2f = W1f + 32768;                         // 32768 frags (512 KB)

    pool_cvt_kernel<<<2304, 256, 0, stream>>>(feature, fs, W1, W2, W1f, W2f);
    att_kernel<<<400, 256, 0, stream>>>(weight, fs, rbuf);
    main_kernel<<<800, 512, 0, stream>>>(feature, rbuf, ln1g, ln1b, W1f, b1,
                                         W2f, b2, ln2g, ln2b, outp);
}

// Round 19
// 156.288 us; speedup vs baseline: 1.2693x; 1.2693x over previous
//
#include <hip/hip_runtime.h>
#include <hip/hip_bf16.h>
#include <math.h>

#define LN_EPS 1e-5f

typedef __attribute__((ext_vector_type(4))) float f4_t;
typedef __attribute__((ext_vector_type(8))) short bf8_t;

__device__ __forceinline__ unsigned short f2bf(float x) {
    unsigned u = __builtin_bit_cast(unsigned, x);
    unsigned r = (u + 0x7FFFu + ((u >> 16) & 1u)) >> 16;
    return (unsigned short)r;
}
__device__ __forceinline__ float bf2f(unsigned short u) {
    return __builtin_bit_cast(float, ((unsigned)u) << 16);
}
// exact GELU: 0.5x(1+erf(x/sqrt2)), erf via A&S 7.1.26 (|eps|<=1.5e-7)
__device__ __forceinline__ float gelu_f(float x) {
    float z = x * 0.70710678f;
    float az = fabsf(z);
    float t = __builtin_amdgcn_rcpf(1.f + 0.3275911f * az);
    float y = t * (0.254829592f + t * (-0.284496736f + t * (1.421413741f +
              t * (-1.453152027f + t * 1.061405429f))));
    float e = 1.f - y * __expf(-az * az);
    return 0.5f * x * (1.f + copysignf(e, x));
}

// LDS-ordering barrier that does not drain vmcnt (global prefetches survive).
__device__ __forceinline__ void light_barrier() {
    asm volatile("s_waitcnt lgkmcnt(0)" ::: "memory");
    __builtin_amdgcn_s_barrier();
}

// ---------------- kernel 1: pool (blocks 0..2047) + weight cvt (2048..2303) ---
__global__ __launch_bounds__(256) void pool_cvt_kernel(
    const float* __restrict__ feature, float* __restrict__ fs,
    const float* __restrict__ W1, const float* __restrict__ W2,
    bf8_t* __restrict__ W1f, bf8_t* __restrict__ W2f) {
    __shared__ float ftile[6400];
    int tid = threadIdx.x;
    if (blockIdx.x >= 2048) {
        int gid = (blockIdx.x - 2048) * 256 + tid;   // 0..65535
        union { bf8_t v; unsigned short u[8]; } pk;
        if (gid < 32768) {
            int lane = gid & 63;
            int f = (gid >> 9) * 16 + (lane & 15);
            int k = ((gid >> 6) & 7) * 32 + (lane >> 4) * 8;
            const float* src = W1 + (size_t)f * 256 + k;
#pragma unroll
            for (int e = 0; e < 8; ++e) pk.u[e] = f2bf(src[e]);
            W1f[gid] = pk.v;
        } else {
            int g = gid - 32768;
            int lane = g & 63;
            int c = (g >> 11) * 16 + (lane & 15);
            int k = ((g >> 6) & 31) * 32 + (lane >> 4) * 8;
            const float* src = W2 + (size_t)c * 1024 + k;
#pragma unroll
            for (int e = 0; e < 8; ++e) pk.u[e] = f2bf(src[e]);
            W2f[g] = pk.v;
        }
        return;
    }
    int b = blockIdx.x;            // n*256 + c
    int n = b >> 8, c = b & 255;
    const float4* src = reinterpret_cast<const float4*>(feature + ((size_t)b) * 6400);
#pragma unroll
    for (int i = 0; i < 6; ++i) {
        int idx = i * 256 + tid;                 // 0..1535
        float4 v = src[idx];
        *reinterpret_cast<float4*>(&ftile[idx * 4]) = v;
    }
    if (tid < 64) {
        int idx = 1536 + tid;
        float4 v = src[idx];
        *reinterpret_cast<float4*>(&ftile[idx * 4]) = v;
    }
    __syncthreads();
    float* dst = fs + (size_t)n * 400 * 256 + c;
#pragma unroll
    for (int pass = 0; pass < 2; ++pass) {
        int k = pass * 256 + tid;
        if (k < 400) {
            int h = k / 20, w = k % 20;
            const float* p = &ftile[(h * 4) * 80 + w * 4];
            float s = 0.f;
#pragma unroll
            for (int dh = 0; dh < 4; ++dh)
                s += p[dh * 80 + 0] + p[dh * 80 + 1] + p[dh * 80 + 2] + p[dh * 80 + 3];
            dst[(size_t)k * 256] = s;
        }
    }
}

// ---------------- kernel 2: r[n][i][c] = sum_k weight[n][i][k] * fs[n][k][c] ---
// 8 rows/block, 64-k LDS chunks, tail-guarded (R17 proven).
__global__ __launch_bounds__(256) void att_kernel(const float* __restrict__ wgt,
                                                  const float* __restrict__ fs,
                                                  float* __restrict__ r) {
    __shared__ float fsl[64][256];   // 64 KB
    __shared__ float wl[8][64];      // 2 KB
    int b = blockIdx.x;
    int n = b / 50, i0 = (b % 50) * 8;
    int tid = threadIdx.x;
    const float* wbase = wgt + (size_t)n * 400 * 400;
    const float* fsbase = fs + (size_t)n * 400 * 256;
    float acc[8] = {0.f, 0.f, 0.f, 0.f, 0.f, 0.f, 0.f, 0.f};
    for (int k0 = 0; k0 < 400; k0 += 64) {
        int kn = (k0 + 64 <= 400) ? 64 : (400 - k0);
        for (int kk = 0; kk < kn; ++kk)
            fsl[kk][tid] = fsbase[(size_t)(k0 + kk) * 256 + tid];
#pragma unroll
        for (int pass = 0; pass < 2; ++pass) {
            int idx = pass * 256 + tid;          // 0..511
            int ii = idx >> 6, kk = idx & 63;
            if (kk < kn)
                wl[ii][kk] = wbase[(size_t)(i0 + ii) * 400 + k0 + kk];
        }
        __syncthreads();
        for (int kk = 0; kk < kn; ++kk) {
            float f = fsl[kk][tid];
#pragma unroll
            for (int ii = 0; ii < 8; ++ii) acc[ii] += wl[ii][kk] * f;
        }
        __syncthreads();
    }
#pragma unroll
    for (int ii = 0; ii < 8; ++ii)
        r[((size_t)n * 400 + i0 + ii) * 256 + tid] = acc[ii];
}

// ---------------- kernel 3: fused residual+att + LN1 + MLP(GELU) + LN2 ---------
// R17 champion structure (64 tokens as two 32-halves sharing B-frags, 4 waves,
// 800 blocks, 3 blocks/CU) + T5 s_setprio(1) around the MFMA clusters:
// 3 waves/SIMD from different blocks at different phases -> scheduler favors
// the MFMA-phase wave (attn-like independent-block regime, m191 +4-7%).
__global__ __launch_bounds__(256, 2) void main_kernel(
    const float* __restrict__ feat, const float* __restrict__ r,
    const float* __restrict__ ln1g, const float* __restrict__ ln1b,
    const bf8_t* __restrict__ W1f, const float* __restrict__ b1,
    const bf8_t* __restrict__ W2f, const float* __restrict__ b2,
    const float* __restrict__ ln2g, const float* __restrict__ ln2b,
    float* __restrict__ out) {
    __shared__ unsigned short xt[64 * 256];      // [t][c] swizzled, 32 KB
    __shared__ unsigned short ht[2][32 * 128];   // per-half [t32][f] swizzled, 2x8 KB
    __shared__ float psum[4][64], psq[4][64];
    __shared__ float stat[2][64];

    int bid = blockIdx.x;
    int n = bid / 100;
    int p0 = (bid % 100) * 64;
    int tid = threadIdx.x;
    int lane = tid & 63;
    int q = tid >> 6;                     // wave id 0..3
    int t = lane;                         // token row (phase 1)
    int p = p0 + t;
    int iatt = ((p / 80) >> 2) * 20 + ((p % 80) >> 2);

    // ---- phase 1 pass 1: x = residual + att -> raw bf16 into xt, stats in regs.
    const float* fbase = feat + ((size_t)(n * 256 + q * 64)) * 6400 + p;
    const float* rrow = r + ((size_t)(n * 400 + iatt)) * 256 + q * 64;
    float s1 = 0.f, s2 = 0.f;
#pragma unroll
    for (int jj = 0; jj < 8; ++jj) {
        union { bf8_t v; unsigned short u[8]; } pk;
#pragma unroll
        for (int e = 0; e < 8; ++e) {
            int j = jj * 8 + e;
            float v = fbase[(size_t)j * 6400] + rrow[j];
            s1 += v;
            s2 += v * v;
            pk.u[e] = f2bf(v);
        }
        int byte = t * 512 + ((q * 128 + jj * 16) ^ ((t & 7) << 4));
        *reinterpret_cast<bf8_t*>(reinterpret_cast<char*>(xt) + byte) = pk.v;
    }
    psum[q][t] = s1;
    psq[q][t] = s2;
    light_barrier();
    if (tid < 64) {
        float a = psum[0][tid] + psum[1][tid] + psum[2][tid] + psum[3][tid];
        float b = psq[0][tid] + psq[1][tid] + psq[2][tid] + psq[3][tid];
        float mu = a * (1.f / 256.f);
        float var = b * (1.f / 256.f) - mu * mu;
        stat[0][tid] = mu;
        stat[1][tid] = rsqrtf(var + LN_EPS);
    }
    light_barrier();
    // ---- phase 1 pass 2: normalize xt in place.
    float mu = stat[0][t], rs = stat[1][t];
#pragma unroll
    for (int jj = 0; jj < 8; ++jj) {
        int byte = t * 512 + ((q * 128 + jj * 16) ^ ((t & 7) << 4));
        union { bf8_t v; unsigned short u[8]; } pk;
        pk.v = *reinterpret_cast<const bf8_t*>(reinterpret_cast<const char*>(xt) + byte);
#pragma unroll
        for (int e = 0; e < 8; ++e) {
            int c = q * 64 + jj * 8 + e;
            float v = bf2f(pk.u[e]);
            pk.u[e] = f2bf((v - mu) * rs * ln1g[c] + ln1b[c]);
        }
        *reinterpret_cast<bf8_t*>(reinterpret_cast<char*>(xt) + byte) = pk.v;
    }
    light_barrier();

    // ---- MFMA phase ----
    int lm = lane & 15, lk = lane >> 4;
    const char* xtb = reinterpret_cast<const char*>(xt);

    f4_t oacc[16];   // [hh*8 + m*4 + cl]
#pragma unroll
    for (int i = 0; i < 16; ++i) oacc[i] = (f4_t){0.f, 0.f, 0.f, 0.f};

    // prologue: prefetch fc=0's kbh=0 W1 batch
    bf8_t bfr0[8];
    {
        const bf8_t* w1p = W1f + ((size_t)(0 * 8 + 2 * q) * 8) * 64 + lane;
#pragma unroll
        for (int kb = 0; kb < 4; ++kb) {
            bfr0[kb * 2 + 0] = w1p[(0 * 8 + kb) * 64];
            bfr0[kb * 2 + 1] = w1p[(1 * 8 + kb) * 64];
        }
    }

    for (int fc = 0; fc < 8; ++fc) {
        const bf8_t* w1p = W1f + ((size_t)(fc * 8 + 2 * q) * 8) * 64 + lane;
        f4_t hacc[8];   // [hh*4 + m*2 + ftl]
#pragma unroll
        for (int i = 0; i < 8; ++i) hacc[i] = (f4_t){0.f, 0.f, 0.f, 0.f};
        __builtin_amdgcn_s_setprio(1);
#pragma unroll
        for (int kbh = 0; kbh < 2; ++kbh) {
            bf8_t bfr[8];
            if (kbh == 0) {
#pragma unroll
                for (int i = 0; i < 8; ++i) bfr[i] = bfr0[i];
            } else {
#pragma unroll
                for (int kb = 0; kb < 4; ++kb) {
                    bfr[kb * 2 + 0] = w1p[(0 * 8 + 4 + kb) * 64];
                    bfr[kb * 2 + 1] = w1p[(1 * 8 + 4 + kb) * 64];
                }
            }
#pragma unroll
            for (int kb = 0; kb < 4; ++kb) {
                int kbb = kbh * 4 + kb;
#pragma unroll
                for (int hh = 0; hh < 2; ++hh) {
#pragma unroll
                    for (int m = 0; m < 2; ++m) {
                        int row = hh * 32 + m * 16 + lm;
                        bf8_t a = *reinterpret_cast<const bf8_t*>(
                            xtb + row * 512 + ((kbb * 64 + lk * 16) ^ ((row & 7) << 4)));
                        hacc[hh * 4 + m * 2 + 0] = __builtin_amdgcn_mfma_f32_16x16x32_bf16(a, bfr[kb * 2 + 0], hacc[hh * 4 + m * 2 + 0], 0, 0, 0);
                        hacc[hh * 4 + m * 2 + 1] = __builtin_amdgcn_mfma_f32_16x16x32_bf16(a, bfr[kb * 2 + 1], hacc[hh * 4 + m * 2 + 1], 0, 0, 0);
                    }
                }
            }
        }
        __builtin_amdgcn_s_setprio(0);
        // issue W2 B-frags for c-tiles {4q,4q+1}; latency hides under the GELUs
        const bf8_t* w2p = W2f + ((size_t)(q * 4) * 32 + fc * 4) * 64 + lane;
        bf8_t b2rA[8];
#pragma unroll
        for (int kb = 0; kb < 4; ++kb) {
            b2rA[kb * 2 + 0] = w2p[(0 * 32 + kb) * 64];
            b2rA[kb * 2 + 1] = w2p[(1 * 32 + kb) * 64];
        }
        // GELU both halves -> ht[0], ht[1] (wave q owns cols (2q..2q+1)*16)
#pragma unroll
        for (int hh = 0; hh < 2; ++hh) {
            char* htc = reinterpret_cast<char*>(ht[hh]);
#pragma unroll
            for (int ftl = 0; ftl < 2; ++ftl) {
                int fl = (2 * q + ftl) * 16 + lm;
                float bias = b1[fc * 128 + fl];
#pragma unroll
                for (int m = 0; m < 2; ++m) {
#pragma unroll
                    for (int j = 0; j < 4; ++j) {
                        int row = m * 16 + lk * 4 + j;   // half-local 0..31
                        float gv = gelu_f(hacc[hh * 4 + m * 2 + ftl][j] + bias);
                        *reinterpret_cast<unsigned short*>(
                            htc + row * 256 + ((fl * 2) ^ ((row & 7) << 4))) = f2bf(gv);
                    }
                }
            }
        }
        light_barrier();   // both ht buffers written
        // second W2 batch + NEXT fc's kbh=0 W1 batch (hide under G2 MFMAs)
        bf8_t b2rB[8];
#pragma unroll
        for (int kb = 0; kb < 4; ++kb) {
            b2rB[kb * 2 + 0] = w2p[(2 * 32 + kb) * 64];
            b2rB[kb * 2 + 1] = w2p[(3 * 32 + kb) * 64];
        }
        if (fc < 7) {
            const bf8_t* w1n = W1f + ((size_t)((fc + 1) * 8 + 2 * q) * 8) * 64 + lane;
#pragma unroll
            for (int kb = 0; kb < 4; ++kb) {
                bfr0[kb * 2 + 0] = w1n[(0 * 8 + kb) * 64];
                bfr0[kb * 2 + 1] = w1n[(1 * 8 + kb) * 64];
            }
        }
        // GEMM2 both halves; B-frags shared
        __builtin_amdgcn_s_setprio(1);
#pragma unroll
        for (int hh = 0; hh < 2; ++hh) {
            const char* htc = reinterpret_cast<const char*>(ht[hh]);
#pragma unroll
            for (int kb = 0; kb < 4; ++kb) {
#pragma unroll
                for (int m = 0; m < 2; ++m) {
                    int row = m * 16 + lm;
                    bf8_t a = *reinterpret_cast<const bf8_t*>(
                        htc + row * 256 + ((kb * 64 + lk * 16) ^ ((row & 7) << 4)));
                    oacc[hh * 8 + m * 4 + 0] = __builtin_amdgcn_mfma_f32_16x16x32_bf16(a, b2rA[kb * 2 + 0], oacc[hh * 8 + m * 4 + 0], 0, 0, 0);
                    oacc[hh * 8 + m * 4 + 1] = __builtin_amdgcn_mfma_f32_16x16x32_bf16(a, b2rA[kb * 2 + 1], oacc[hh * 8 + m * 4 + 1], 0, 0, 0);
                    oacc[hh * 8 + m * 4 + 2] = __builtin_amdgcn_mfma_f32_16x16x32_bf16(a, b2rB[kb * 2 + 0], oacc[hh * 8 + m * 4 + 2], 0, 0, 0);
                    oacc[hh * 8 + m * 4 + 3] = __builtin_amdgcn_mfma_f32_16x16x32_bf16(a, b2rB[kb * 2 + 1], oacc[hh * 8 + m * 4 + 3], 0, 0, 0);
                }
            }
        }
        __builtin_amdgcn_s_setprio(0);
        light_barrier();   // all ht reads done before next fc's GELU writes
    }

    // ---- epilogue: + b2 + residual2, LN2, store. Wave q owns c (4q..4q+3)*16.
    float b2l[4];
#pragma unroll
    for (int cl = 0; cl < 4; ++cl) b2l[cl] = b2[(q * 4 + cl) * 16 + lm];
#pragma unroll
    for (int hh = 0; hh < 2; ++hh) {
#pragma unroll
        for (int m = 0; m < 2; ++m) {
#pragma unroll
            for (int j = 0; j < 4; ++j) {
                int row = hh * 32 + m * 16 + lk * 4 + j;
                float s = 0.f, ss = 0.f;
#pragma unroll
                for (int cl = 0; cl < 4; ++cl) {
                    int c = (q * 4 + cl) * 16 + lm;
                    float res = bf2f(*reinterpret_cast<const unsigned short*>(
                        xtb + row * 512 + ((c * 2) ^ ((row & 7) << 4))));
                    float v = oacc[hh * 8 + m * 4 + cl][j] + b2l[cl] + res;
                    oacc[hh * 8 + m * 4 + cl][j] = v;
                    s += v;
                    ss += v * v;
                }
#pragma unroll
                for (int d = 1; d < 16; d <<= 1) {
                    s += __shfl_xor(s, d, 64);
                    ss += __shfl_xor(ss, d, 64);
                }
                if (lm == 0) { psum[q][row] = s; psq[q][row] = ss; }
            }
        }
    }
    light_barrier();
    if (tid < 64) {
        float a = psum[0][tid] + psum[1][tid] + psum[2][tid] + psum[3][tid];
        float b = psq[0][tid] + psq[1][tid] + psq[2][tid] + psq[3][tid];
        float mu2 = a * (1.f / 256.f);
        float var = b * (1.f / 256.f) - mu2 * mu2;
        stat[0][tid] = mu2;
        stat[1][tid] = rsqrtf(var + LN_EPS);
    }
    light_barrier();
    float g2[4], be2[4];
#pragma unroll
    for (int cl = 0; cl < 4; ++cl) {
        int c = (q * 4 + cl) * 16 + lm;
        g2[cl] = ln2g[c];
        be2[cl] = ln2b[c];
    }
    float* obase = out + ((size_t)(n * 6400 + p0)) * 256;
#pragma unroll
    for (int hh = 0; hh < 2; ++hh) {
#pragma unroll
        for (int m = 0; m < 2; ++m) {
#pragma unroll
            for (int j = 0; j < 4; ++j) {
                int row = hh * 32 + m * 16 + lk * 4 + j;
                float mu2 = stat[0][row], r2 = stat[1][row];
#pragma unroll
                for (int cl = 0; cl < 4; ++cl) {
                    int c = (q * 4 + cl) * 16 + lm;
                    obase[(size_t)row * 256 + c] =
                        (oacc[hh * 8 + m * 4 + cl][j] - mu2) * r2 * g2[cl] + be2[cl];
                }
            }
        }
    }
}

extern "C" void kernel_launch(void* const* d_in, const int* in_sizes, int n_in,
                              void* d_out, int out_size, void* d_ws, size_t ws_size,
                              hipStream_t stream) {
    const float* weight = (const float*)d_in[0];   // [8,400,400]
    const float* feature = (const float*)d_in[1];  // [8,256,80,80]
    const float* ln1g = (const float*)d_in[2];
    const float* ln1b = (const float*)d_in[3];
    const float* W1 = (const float*)d_in[4];       // [1024,256]
    const float* b1 = (const float*)d_in[5];
    const float* W2 = (const float*)d_in[6];       // [256,1024]
    const float* b2 = (const float*)d_in[7];
    const float* ln2g = (const float*)d_in[8];
    const float* ln2b = (const float*)d_in[9];
    float* outp = (float*)d_out;

    float* fs = (float*)d_ws;                         // 819200 f32
    float* rbuf = fs + 819200;                        // 819200 f32
    bf8_t* W1f = (bf8_t*)(rbuf + 819200);             // 32768 frags (512 KB)
    bf8_t* W2f = W1f + 32768;                         // 32768 frags (512 KB)

    pool_cvt_kernel<<<2304, 256, 0, stream>>>(feature, fs, W1, W2, W1f, W2f);
    att_kernel<<<400, 256, 0, stream>>>(weight, fs, rbuf);
    main_kernel<<<800, 256, 0, stream>>>(feature, rbuf, ln1g, ln1b, W1f, b1,
                                         W2f, b2, ln2g, ln2b, outp);
}

// Round 20
// 146.487 us; speedup vs baseline: 1.3542x; 1.0669x over previous
//
#include <hip/hip_runtime.h>
#include <hip/hip_bf16.h>
#include <math.h>

#define LN_EPS 1e-5f

typedef __attribute__((ext_vector_type(4))) float f4_t;
typedef __attribute__((ext_vector_type(8))) short bf8_t;

__device__ __forceinline__ unsigned short f2bf(float x) {
    unsigned u = __builtin_bit_cast(unsigned, x);
    unsigned r = (u + 0x7FFFu + ((u >> 16) & 1u)) >> 16;
    return (unsigned short)r;
}
__device__ __forceinline__ float bf2f(unsigned short u) {
    return __builtin_bit_cast(float, ((unsigned)u) << 16);
}
// exact GELU: 0.5x(1+erf(x/sqrt2)), erf via A&S 7.1.26 (|eps|<=1.5e-7)
__device__ __forceinline__ float gelu_f(float x) {
    float z = x * 0.70710678f;
    float az = fabsf(z);
    float t = __builtin_amdgcn_rcpf(1.f + 0.3275911f * az);
    float y = t * (0.254829592f + t * (-0.284496736f + t * (1.421413741f +
              t * (-1.453152027f + t * 1.061405429f))));
    float e = 1.f - y * __expf(-az * az);
    return 0.5f * x * (1.f + copysignf(e, x));
}

// LDS-ordering barrier that does not drain vmcnt (global prefetches survive).
__device__ __forceinline__ void light_barrier() {
    asm volatile("s_waitcnt lgkmcnt(0)" ::: "memory");
    __builtin_amdgcn_s_barrier();
}

// ---------------- kernel 1: pool (blocks 0..2047) + weight cvt (2048..2303) ---
__global__ __launch_bounds__(256) void pool_cvt_kernel(
    const float* __restrict__ feature, float* __restrict__ fs,
    const float* __restrict__ W1, const float* __restrict__ W2,
    bf8_t* __restrict__ W1f, bf8_t* __restrict__ W2f) {
    __shared__ float ftile[6400];
    int tid = threadIdx.x;
    if (blockIdx.x >= 2048) {
        int gid = (blockIdx.x - 2048) * 256 + tid;   // 0..65535
        union { bf8_t v; unsigned short u[8]; } pk;
        if (gid < 32768) {
            int lane = gid & 63;
            int f = (gid >> 9) * 16 + (lane & 15);
            int k = ((gid >> 6) & 7) * 32 + (lane >> 4) * 8;
            const float* src = W1 + (size_t)f * 256 + k;
#pragma unroll
            for (int e = 0; e < 8; ++e) pk.u[e] = f2bf(src[e]);
            W1f[gid] = pk.v;
        } else {
            int g = gid - 32768;
            int lane = g & 63;
            int c = (g >> 11) * 16 + (lane & 15);
            int k = ((g >> 6) & 31) * 32 + (lane >> 4) * 8;
            const float* src = W2 + (size_t)c * 1024 + k;
#pragma unroll
            for (int e = 0; e < 8; ++e) pk.u[e] = f2bf(src[e]);
            W2f[g] = pk.v;
        }
        return;
    }
    int b = blockIdx.x;            // n*256 + c
    int n = b >> 8, c = b & 255;
    const float4* src = reinterpret_cast<const float4*>(feature + ((size_t)b) * 6400);
#pragma unroll
    for (int i = 0; i < 6; ++i) {
        int idx = i * 256 + tid;                 // 0..1535
        float4 v = src[idx];
        *reinterpret_cast<float4*>(&ftile[idx * 4]) = v;
    }
    if (tid < 64) {
        int idx = 1536 + tid;
        float4 v = src[idx];
        *reinterpret_cast<float4*>(&ftile[idx * 4]) = v;
    }
    __syncthreads();
    float* dst = fs + (size_t)n * 400 * 256 + c;
#pragma unroll
    for (int pass = 0; pass < 2; ++pass) {
        int k = pass * 256 + tid;
        if (k < 400) {
            int h = k / 20, w = k % 20;
            const float* p = &ftile[(h * 4) * 80 + w * 4];
            float s = 0.f;
#pragma unroll
            for (int dh = 0; dh < 4; ++dh)
                s += p[dh * 80 + 0] + p[dh * 80 + 1] + p[dh * 80 + 2] + p[dh * 80 + 3];
            dst[(size_t)k * 256] = s;
        }
    }
}

// ---------------- kernel 2: att via MFMA: R[400x256] = W[400x400]·FS[400x256] --
// per n, bf16 inputs / f32 accum. 400 blocks = 8n x 25 M-tiles x 2 c-halves.
// Per 32-k chunk: stage fs chunk -> LDS bf16 [k][c] linear; a-frags loaded
// straight from W f32 (16 rows x 32 k tile, read once chip-wide); K-tail
// zero-padded (400 -> 13 chunks).
__global__ __launch_bounds__(256) void att_kernel(const float* __restrict__ wgt,
                                                  const float* __restrict__ fs,
                                                  float* __restrict__ r) {
    __shared__ unsigned short fsl[32 * 128];   // [k][c] bf16 linear, 8 KB
    int b = blockIdx.x;                 // 0..399
    int n = b / 50;
    int rem = b % 50;
    int i0 = (rem >> 1) * 16;
    int cb = (rem & 1) * 128;
    int tid = threadIdx.x;
    int lane = tid & 63;
    int q = tid >> 6;                   // wave 0..3
    int lm = lane & 15, lk = lane >> 4;
    const float* wbase = wgt + (size_t)n * 400 * 400 + (size_t)(i0 + lm) * 400;
    const float* fsb = fs + (size_t)n * 400 * 256 + cb;
    f4_t acc[2];
    acc[0] = (f4_t){0.f, 0.f, 0.f, 0.f};
    acc[1] = (f4_t){0.f, 0.f, 0.f, 0.f};
    for (int kc = 0; kc < 13; ++kc) {
        int k0 = kc * 32;
        // stage fs[k0..k0+31][cb..cb+127] -> fsl (zeros past k=399)
#pragma unroll
        for (int r4 = 0; r4 < 4; ++r4) {
            int idx = r4 * 256 + tid;       // 0..1023
            int k = idx >> 5;               // 0..31
            int c4 = (idx & 31) * 4;
            float4 v;
            if (k0 + k < 400)
                v = *reinterpret_cast<const float4*>(fsb + (size_t)(k0 + k) * 256 + c4);
            else
                v = make_float4(0.f, 0.f, 0.f, 0.f);
            unsigned short* d = &fsl[k * 128 + c4];
            d[0] = f2bf(v.x); d[1] = f2bf(v.y); d[2] = f2bf(v.z); d[3] = f2bf(v.w);
        }
        // a-frag: lane lm = row i, k = k0 + lk*8 + e (zeros past 399)
        union { bf8_t v; unsigned short u[8]; } af;
        int ka = k0 + lk * 8;
        if (ka < 400) {
#pragma unroll
            for (int e = 0; e < 8; ++e) af.u[e] = f2bf(wbase[ka + e]);
        } else {
#pragma unroll
            for (int e = 0; e < 8; ++e) af.u[e] = 0;
        }
        light_barrier();
        // b-frags from fsl + MFMA; wave q owns c-tiles {2q, 2q+1}
#pragma unroll
        for (int ntl = 0; ntl < 2; ++ntl) {
            int c = (q * 2 + ntl) * 16 + lm;
            union { bf8_t v; unsigned short u[8]; } bf;
#pragma unroll
            for (int e = 0; e < 8; ++e) bf.u[e] = fsl[(lk * 8 + e) * 128 + c];
            acc[ntl] = __builtin_amdgcn_mfma_f32_16x16x32_bf16(af.v, bf.v, acc[ntl], 0, 0, 0);
        }
        light_barrier();   // fsl reads done before next chunk's writes
    }
    // store: D row = lk*4+j, col = lm
    float* rb = r + ((size_t)n * 400 + i0) * 256 + cb;
#pragma unroll
    for (int ntl = 0; ntl < 2; ++ntl) {
        int c = (q * 2 + ntl) * 16 + lm;
#pragma unroll
        for (int j = 0; j < 4; ++j)
            rb[(size_t)(lk * 4 + j) * 256 + c] = acc[ntl][j];
    }
}

// ---------------- kernel 3: fused residual+att + LN1 + MLP(GELU) + LN2 ---------
// R17 champion structure exactly (64 tokens as two 32-halves sharing B-frags,
// 4 waves, 800 blocks, 3 blocks/CU, next-fc W1 prefetch, light barriers).
__global__ __launch_bounds__(256, 2) void main_kernel(
    const float* __restrict__ feat, const float* __restrict__ r,
    const float* __restrict__ ln1g, const float* __restrict__ ln1b,
    const bf8_t* __restrict__ W1f, const float* __restrict__ b1,
    const bf8_t* __restrict__ W2f, const float* __restrict__ b2,
    const float* __restrict__ ln2g, const float* __restrict__ ln2b,
    float* __restrict__ out) {
    __shared__ unsigned short xt[64 * 256];      // [t][c] swizzled, 32 KB
    __shared__ unsigned short ht[2][32 * 128];   // per-half [t32][f] swizzled, 2x8 KB
    __shared__ float psum[4][64], psq[4][64];
    __shared__ float stat[2][64];

    int bid = blockIdx.x;
    int n = bid / 100;
    int p0 = (bid % 100) * 64;
    int tid = threadIdx.x;
    int lane = tid & 63;
    int q = tid >> 6;                     // wave id 0..3
    int t = lane;                         // token row (phase 1)
    int p = p0 + t;
    int iatt = ((p / 80) >> 2) * 20 + ((p % 80) >> 2);

    // ---- phase 1 pass 1: x = residual + att -> raw bf16 into xt, stats in regs.
    const float* fbase = feat + ((size_t)(n * 256 + q * 64)) * 6400 + p;
    const float* rrow = r + ((size_t)(n * 400 + iatt)) * 256 + q * 64;
    float s1 = 0.f, s2 = 0.f;
#pragma unroll
    for (int jj = 0; jj < 8; ++jj) {
        union { bf8_t v; unsigned short u[8]; } pk;
#pragma unroll
        for (int e = 0; e < 8; ++e) {
            int j = jj * 8 + e;
            float v = fbase[(size_t)j * 6400] + rrow[j];
            s1 += v;
            s2 += v * v;
            pk.u[e] = f2bf(v);
        }
        int byte = t * 512 + ((q * 128 + jj * 16) ^ ((t & 7) << 4));
        *reinterpret_cast<bf8_t*>(reinterpret_cast<char*>(xt) + byte) = pk.v;
    }
    psum[q][t] = s1;
    psq[q][t] = s2;
    light_barrier();
    if (tid < 64) {
        float a = psum[0][tid] + psum[1][tid] + psum[2][tid] + psum[3][tid];
        float b = psq[0][tid] + psq[1][tid] + psq[2][tid] + psq[3][tid];
        float mu = a * (1.f / 256.f);
        float var = b * (1.f / 256.f) - mu * mu;
        stat[0][tid] = mu;
        stat[1][tid] = rsqrtf(var + LN_EPS);
    }
    light_barrier();
    // ---- phase 1 pass 2: normalize xt in place.
    float mu = stat[0][t], rs = stat[1][t];
#pragma unroll
    for (int jj = 0; jj < 8; ++jj) {
        int byte = t * 512 + ((q * 128 + jj * 16) ^ ((t & 7) << 4));
        union { bf8_t v; unsigned short u[8]; } pk;
        pk.v = *reinterpret_cast<const bf8_t*>(reinterpret_cast<const char*>(xt) + byte);
#pragma unroll
        for (int e = 0; e < 8; ++e) {
            int c = q * 64 + jj * 8 + e;
            float v = bf2f(pk.u[e]);
            pk.u[e] = f2bf((v - mu) * rs * ln1g[c] + ln1b[c]);
        }
        *reinterpret_cast<bf8_t*>(reinterpret_cast<char*>(xt) + byte) = pk.v;
    }
    light_barrier();

    // ---- MFMA phase ----
    int lm = lane & 15, lk = lane >> 4;
    const char* xtb = reinterpret_cast<const char*>(xt);

    f4_t oacc[16];   // [hh*8 + m*4 + cl]
#pragma unroll
    for (int i = 0; i < 16; ++i) oacc[i] = (f4_t){0.f, 0.f, 0.f, 0.f};

    // prologue: prefetch fc=0's kbh=0 W1 batch
    bf8_t bfr0[8];
    {
        const bf8_t* w1p = W1f + ((size_t)(0 * 8 + 2 * q) * 8) * 64 + lane;
#pragma unroll
        for (int kb = 0; kb < 4; ++kb) {
            bfr0[kb * 2 + 0] = w1p[(0 * 8 + kb) * 64];
            bfr0[kb * 2 + 1] = w1p[(1 * 8 + kb) * 64];
        }
    }

    for (int fc = 0; fc < 8; ++fc) {
        const bf8_t* w1p = W1f + ((size_t)(fc * 8 + 2 * q) * 8) * 64 + lane;
        f4_t hacc[8];   // [hh*4 + m*2 + ftl]
#pragma unroll
        for (int i = 0; i < 8; ++i) hacc[i] = (f4_t){0.f, 0.f, 0.f, 0.f};
#pragma unroll
        for (int kbh = 0; kbh < 2; ++kbh) {
            bf8_t bfr[8];
            if (kbh == 0) {
#pragma unroll
                for (int i = 0; i < 8; ++i) bfr[i] = bfr0[i];
            } else {
#pragma unroll
                for (int kb = 0; kb < 4; ++kb) {
                    bfr[kb * 2 + 0] = w1p[(0 * 8 + 4 + kb) * 64];
                    bfr[kb * 2 + 1] = w1p[(1 * 8 + 4 + kb) * 64];
                }
            }
#pragma unroll
            for (int kb = 0; kb < 4; ++kb) {
                int kbb = kbh * 4 + kb;
#pragma unroll
                for (int hh = 0; hh < 2; ++hh) {
#pragma unroll
                    for (int m = 0; m < 2; ++m) {
                        int row = hh * 32 + m * 16 + lm;
                        bf8_t a = *reinterpret_cast<const bf8_t*>(
                            xtb + row * 512 + ((kbb * 64 + lk * 16) ^ ((row & 7) << 4)));
                        hacc[hh * 4 + m * 2 + 0] = __builtin_amdgcn_mfma_f32_16x16x32_bf16(a, bfr[kb * 2 + 0], hacc[hh * 4 + m * 2 + 0], 0, 0, 0);
                        hacc[hh * 4 + m * 2 + 1] = __builtin_amdgcn_mfma_f32_16x16x32_bf16(a, bfr[kb * 2 + 1], hacc[hh * 4 + m * 2 + 1], 0, 0, 0);
                    }
                }
            }
        }
        // issue W2 B-frags for c-tiles {4q,4q+1}; latency hides under the GELUs
        const bf8_t* w2p = W2f + ((size_t)(q * 4) * 32 + fc * 4) * 64 + lane;
        bf8_t b2rA[8];
#pragma unroll
        for (int kb = 0; kb < 4; ++kb) {
            b2rA[kb * 2 + 0] = w2p[(0 * 32 + kb) * 64];
            b2rA[kb * 2 + 1] = w2p[(1 * 32 + kb) * 64];
        }
        // GELU both halves -> ht[0], ht[1] (wave q owns cols (2q..2q+1)*16)
#pragma unroll
        for (int hh = 0; hh < 2; ++hh) {
            char* htc = reinterpret_cast<char*>(ht[hh]);
#pragma unroll
            for (int ftl = 0; ftl < 2; ++ftl) {
                int fl = (2 * q + ftl) * 16 + lm;
                float bias = b1[fc * 128 + fl];
#pragma unroll
                for (int m = 0; m < 2; ++m) {
#pragma unroll
                    for (int j = 0; j < 4; ++j) {
                        int row = m * 16 + lk * 4 + j;   // half-local 0..31
                        float gv = gelu_f(hacc[hh * 4 + m * 2 + ftl][j] + bias);
                        *reinterpret_cast<unsigned short*>(
                            htc + row * 256 + ((fl * 2) ^ ((row & 7) << 4))) = f2bf(gv);
                    }
                }
            }
        }
        light_barrier();   // both ht buffers written
        // second W2 batch + NEXT fc's kbh=0 W1 batch (hide under G2 MFMAs)
        bf8_t b2rB[8];
#pragma unroll
        for (int kb = 0; kb < 4; ++kb) {
            b2rB[kb * 2 + 0] = w2p[(2 * 32 + kb) * 64];
            b2rB[kb * 2 + 1] = w2p[(3 * 32 + kb) * 64];
        }
        if (fc < 7) {
            const bf8_t* w1n = W1f + ((size_t)((fc + 1) * 8 + 2 * q) * 8) * 64 + lane;
#pragma unroll
            for (int kb = 0; kb < 4; ++kb) {
                bfr0[kb * 2 + 0] = w1n[(0 * 8 + kb) * 64];
                bfr0[kb * 2 + 1] = w1n[(1 * 8 + kb) * 64];
            }
        }
        // GEMM2 both halves; B-frags shared
#pragma unroll
        for (int hh = 0; hh < 2; ++hh) {
            const char* htc = reinterpret_cast<const char*>(ht[hh]);
#pragma unroll
            for (int kb = 0; kb < 4; ++kb) {
#pragma unroll
                for (int m = 0; m < 2; ++m) {
                    int row = m * 16 + lm;
                    bf8_t a = *reinterpret_cast<const bf8_t*>(
                        htc + row * 256 + ((kb * 64 + lk * 16) ^ ((row & 7) << 4)));
                    oacc[hh * 8 + m * 4 + 0] = __builtin_amdgcn_mfma_f32_16x16x32_bf16(a, b2rA[kb * 2 + 0], oacc[hh * 8 + m * 4 + 0], 0, 0, 0);
                    oacc[hh * 8 + m * 4 + 1] = __builtin_amdgcn_mfma_f32_16x16x32_bf16(a, b2rA[kb * 2 + 1], oacc[hh * 8 + m * 4 + 1], 0, 0, 0);
                    oacc[hh * 8 + m * 4 + 2] = __builtin_amdgcn_mfma_f32_16x16x32_bf16(a, b2rB[kb * 2 + 0], oacc[hh * 8 + m * 4 + 2], 0, 0, 0);
                    oacc[hh * 8 + m * 4 + 3] = __builtin_amdgcn_mfma_f32_16x16x32_bf16(a, b2rB[kb * 2 + 1], oacc[hh * 8 + m * 4 + 3], 0, 0, 0);
                }
            }
        }
        light_barrier();   // all ht reads done before next fc's GELU writes
    }

    // ---- epilogue: + b2 + residual2, LN2, store. Wave q owns c (4q..4q+3)*16.
    float b2l[4];
#pragma unroll
    for (int cl = 0; cl < 4; ++cl) b2l[cl] = b2[(q * 4 + cl) * 16 + lm];
#pragma unroll
    for (int hh = 0; hh < 2; ++hh) {
#pragma unroll
        for (int m = 0; m < 2; ++m) {
#pragma unroll
            for (int j = 0; j < 4; ++j) {
                int row = hh * 32 + m * 16 + lk * 4 + j;
                float s = 0.f, ss = 0.f;
#pragma unroll
                for (int cl = 0; cl < 4; ++cl) {
                    int c = (q * 4 + cl) * 16 + lm;
                    float res = bf2f(*reinterpret_cast<const unsigned short*>(
                        xtb + row * 512 + ((c * 2) ^ ((row & 7) << 4))));
                    float v = oacc[hh * 8 + m * 4 + cl][j] + b2l[cl] + res;
                    oacc[hh * 8 + m * 4 + cl][j] = v;
                    s += v;
                    ss += v * v;
                }
#pragma unroll
                for (int d = 1; d < 16; d <<= 1) {
                    s += __shfl_xor(s, d, 64);
                    ss += __shfl_xor(ss, d, 64);
                }
                if (lm == 0) { psum[q][row] = s; psq[q][row] = ss; }
            }
        }
    }
    light_barrier();
    if (tid < 64) {
        float a = psum[0][tid] + psum[1][tid] + psum[2][tid] + psum[3][tid];
        float b = psq[0][tid] + psq[1][tid] + psq[2][tid] + psq[3][tid];
        float mu2 = a * (1.f / 256.f);
        float var = b * (1.f / 256.f) - mu2 * mu2;
        stat[0][tid] = mu2;
        stat[1][tid] = rsqrtf(var + LN_EPS);
    }
    light_barrier();
    float g2[4], be2[4];
#pragma unroll
    for (int cl = 0; cl < 4; ++cl) {
        int c = (q * 4 + cl) * 16 + lm;
        g2[cl] = ln2g[c];
        be2[cl] = ln2b[c];
    }
    float* obase = out + ((size_t)(n * 6400 + p0)) * 256;
#pragma unroll
    for (int hh = 0; hh < 2; ++hh) {
#pragma unroll
        for (int m = 0; m < 2; ++m) {
#pragma unroll
            for (int j = 0; j < 4; ++j) {
                int row = hh * 32 + m * 16 + lk * 4 + j;
                float mu2 = stat[0][row], r2 = stat[1][row];
#pragma unroll
                for (int cl = 0; cl < 4; ++cl) {
                    int c = (q * 4 + cl) * 16 + lm;
                    obase[(size_t)row * 256 + c] =
                        (oacc[hh * 8 + m * 4 + cl][j] - mu2) * r2 * g2[cl] + be2[cl];
                }
            }
        }
    }
}

extern "C" void kernel_launch(void* const* d_in, const int* in_sizes, int n_in,
                              void* d_out, int out_size, void* d_ws, size_t ws_size,
                              hipStream_t stream) {
    const float* weight = (const float*)d_in[0];   // [8,400,400]
    const float* feature = (const float*)d_in[1];  // [8,256,80,80]
    const float* ln1g = (const float*)d_in[2];
    const float* ln1b = (const float*)d_in[3];
    const float* W1 = (const float*)d_in[4];       // [1024,256]
    const float* b1 = (const float*)d_in[5];
    const float* W2 = (const float*)d_in[6];       // [256,1024]
    const float* b2 = (const float*)d_in[7];
    const float* ln2g = (const float*)d_in[8];
    const float* ln2b = (const float*)d_in[9];
    float* outp = (float*)d_out;

    float* fs = (float*)d_ws;                         // 819200 f32
    float* rbuf = fs + 819200;                        // 819200 f32
    bf8_t* W1f = (bf8_t*)(rbuf + 819200);             // 32768 frags (512 KB)
    bf8_t* W2f = W1f + 32768;                         // 32768 frags (512 KB)

    pool_cvt_kernel<<<2304, 256, 0, stream>>>(feature, fs, W1, W2, W1f, W2f);
    att_kernel<<<400, 256, 0, stream>>>(weight, fs, rbuf);
    main_kernel<<<800, 256, 0, stream>>>(feature, rbuf, ln1g, ln1b, W1f, b1,
                                         W2f, b2, ln2g, ln2b, outp);
}

// Round 21
// 142.939 us; speedup vs baseline: 1.3879x; 1.0248x over previous
//
#include <hip/hip_runtime.h>
#include <hip/hip_bf16.h>
#include <math.h>

#define LN_EPS 1e-5f

typedef __attribute__((ext_vector_type(4))) float f4_t;
typedef __attribute__((ext_vector_type(8))) short bf8_t;
typedef __attribute__((ext_vector_type(4))) unsigned short us4_t;

__device__ __forceinline__ unsigned short f2bf(float x) {
    unsigned u = __builtin_bit_cast(unsigned, x);
    unsigned r = (u + 0x7FFFu + ((u >> 16) & 1u)) >> 16;
    return (unsigned short)r;
}
__device__ __forceinline__ float bf2f(unsigned short u) {
    return __builtin_bit_cast(float, ((unsigned)u) << 16);
}
// exact GELU: 0.5x(1+erf(x/sqrt2)), erf via A&S 7.1.26 (|eps|<=1.5e-7)
__device__ __forceinline__ float gelu_f(float x) {
    float z = x * 0.70710678f;
    float az = fabsf(z);
    float t = __builtin_amdgcn_rcpf(1.f + 0.3275911f * az);
    float y = t * (0.254829592f + t * (-0.284496736f + t * (1.421413741f +
              t * (-1.453152027f + t * 1.061405429f))));
    float e = 1.f - y * __expf(-az * az);
    return 0.5f * x * (1.f + copysignf(e, x));
}

// LDS-ordering barrier that does not drain vmcnt (global prefetches survive).
__device__ __forceinline__ void light_barrier() {
    asm volatile("s_waitcnt lgkmcnt(0)" ::: "memory");
    __builtin_amdgcn_s_barrier();
}

// ---------------- kernel 1: pool (blocks 0..2047) + weight cvt (2048..2303) ---
// pool now stores fs directly as bf16 (same value att would have rounded to).
__global__ __launch_bounds__(256) void pool_cvt_kernel(
    const float* __restrict__ feature, unsigned short* __restrict__ fs,
    const float* __restrict__ W1, const float* __restrict__ W2,
    bf8_t* __restrict__ W1f, bf8_t* __restrict__ W2f) {
    __shared__ float ftile[6400];
    int tid = threadIdx.x;
    if (blockIdx.x >= 2048) {
        int gid = (blockIdx.x - 2048) * 256 + tid;   // 0..65535
        union { bf8_t v; unsigned short u[8]; } pk;
        if (gid < 32768) {
            int lane = gid & 63;
            int f = (gid >> 9) * 16 + (lane & 15);
            int k = ((gid >> 6) & 7) * 32 + (lane >> 4) * 8;
            const float* src = W1 + (size_t)f * 256 + k;
#pragma unroll
            for (int e = 0; e < 8; ++e) pk.u[e] = f2bf(src[e]);
            W1f[gid] = pk.v;
        } else {
            int g = gid - 32768;
            int lane = g & 63;
            int c = (g >> 11) * 16 + (lane & 15);
            int k = ((g >> 6) & 31) * 32 + (lane >> 4) * 8;
            const float* src = W2 + (size_t)c * 1024 + k;
#pragma unroll
            for (int e = 0; e < 8; ++e) pk.u[e] = f2bf(src[e]);
            W2f[g] = pk.v;
        }
        return;
    }
    int b = blockIdx.x;            // n*256 + c
    int n = b >> 8, c = b & 255;
    const float4* src = reinterpret_cast<const float4*>(feature + ((size_t)b) * 6400);
#pragma unroll
    for (int i = 0; i < 6; ++i) {
        int idx = i * 256 + tid;                 // 0..1535
        float4 v = src[idx];
        *reinterpret_cast<float4*>(&ftile[idx * 4]) = v;
    }
    if (tid < 64) {
        int idx = 1536 + tid;
        float4 v = src[idx];
        *reinterpret_cast<float4*>(&ftile[idx * 4]) = v;
    }
    __syncthreads();
    unsigned short* dst = fs + (size_t)n * 400 * 256 + c;
#pragma unroll
    for (int pass = 0; pass < 2; ++pass) {
        int k = pass * 256 + tid;
        if (k < 400) {
            int h = k / 20, w = k % 20;
            const float* p = &ftile[(h * 4) * 80 + w * 4];
            float s = 0.f;
#pragma unroll
            for (int dh = 0; dh < 4; ++dh)
                s += p[dh * 80 + 0] + p[dh * 80 + 1] + p[dh * 80 + 2] + p[dh * 80 + 3];
            dst[(size_t)k * 256] = f2bf(s);
        }
    }
}

// ---------------- kernel 2: att via MFMA: R[400x256] = W[400x400]·FS[400x256] --
// fs already bf16 -> staging is a pure ushort copy (no cvt VALU, half bytes).
__global__ __launch_bounds__(256) void att_kernel(const float* __restrict__ wgt,
                                                  const unsigned short* __restrict__ fs,
                                                  float* __restrict__ r) {
    __shared__ unsigned short fsl[32 * 128];   // [k][c] bf16 linear, 8 KB
    int b = blockIdx.x;                 // 0..399
    int n = b / 50;
    int rem = b % 50;
    int i0 = (rem >> 1) * 16;
    int cb = (rem & 1) * 128;
    int tid = threadIdx.x;
    int lane = tid & 63;
    int q = tid >> 6;                   // wave 0..3
    int lm = lane & 15, lk = lane >> 4;
    const float* wbase = wgt + (size_t)n * 400 * 400 + (size_t)(i0 + lm) * 400;
    const unsigned short* fsb = fs + (size_t)n * 400 * 256 + cb;
    f4_t acc[2];
    acc[0] = (f4_t){0.f, 0.f, 0.f, 0.f};
    acc[1] = (f4_t){0.f, 0.f, 0.f, 0.f};
    for (int kc = 0; kc < 13; ++kc) {
        int k0 = kc * 32;
        // stage fs[k0..k0+31][cb..cb+127] -> fsl (zeros past k=399)
#pragma unroll
        for (int r4 = 0; r4 < 4; ++r4) {
            int idx = r4 * 256 + tid;       // 0..1023
            int k = idx >> 5;               // 0..31
            int c4 = (idx & 31) * 4;
            us4_t v;
            if (k0 + k < 400)
                v = *reinterpret_cast<const us4_t*>(fsb + (size_t)(k0 + k) * 256 + c4);
            else
                v = (us4_t){0, 0, 0, 0};
            *reinterpret_cast<us4_t*>(&fsl[k * 128 + c4]) = v;
        }
        // a-frag: lane lm = row i, k = k0 + lk*8 + e (zeros past 399)
        union { bf8_t v; unsigned short u[8]; } af;
        int ka = k0 + lk * 8;
        if (ka < 400) {
#pragma unroll
            for (int e = 0; e < 8; ++e) af.u[e] = f2bf(wbase[ka + e]);
        } else {
#pragma unroll
            for (int e = 0; e < 8; ++e) af.u[e] = 0;
        }
        light_barrier();
        // b-frags from fsl + MFMA; wave q owns c-tiles {2q, 2q+1}
#pragma unroll
        for (int ntl = 0; ntl < 2; ++ntl) {
            int c = (q * 2 + ntl) * 16 + lm;
            union { bf8_t v; unsigned short u[8]; } bf;
#pragma unroll
            for (int e = 0; e < 8; ++e) bf.u[e] = fsl[(lk * 8 + e) * 128 + c];
            acc[ntl] = __builtin_amdgcn_mfma_f32_16x16x32_bf16(af.v, bf.v, acc[ntl], 0, 0, 0);
        }
        light_barrier();   // fsl reads done before next chunk's writes
    }
    // store: D row = lk*4+j, col = lm
    float* rb = r + ((size_t)n * 400 + i0) * 256 + cb;
#pragma unroll
    for (int ntl = 0; ntl < 2; ++ntl) {
        int c = (q * 2 + ntl) * 16 + lm;
#pragma unroll
        for (int j = 0; j < 4; ++j)
            rb[(size_t)(lk * 4 + j) * 256 + c] = acc[ntl][j];
    }
}

// ---------------- kernel 3: fused residual+att + LN1 + MLP(GELU) + LN2 ---------
// R17/R20 champion structure exactly (64 tokens as two 32-halves sharing
// B-frags, 4 waves, 800 blocks, 3 blocks/CU, next-fc W1 prefetch).
__global__ __launch_bounds__(256, 2) void main_kernel(
    const float* __restrict__ feat, const float* __restrict__ r,
    const float* __restrict__ ln1g, const float* __restrict__ ln1b,
    const bf8_t* __restrict__ W1f, const float* __restrict__ b1,
    const bf8_t* __restrict__ W2f, const float* __restrict__ b2,
    const float* __restrict__ ln2g, const float* __restrict__ ln2b,
    float* __restrict__ out) {
    __shared__ unsigned short xt[64 * 256];      // [t][c] swizzled, 32 KB
    __shared__ unsigned short ht[2][32 * 128];   // per-half [t32][f] swizzled, 2x8 KB
    __shared__ float psum[4][64], psq[4][64];
    __shared__ float stat[2][64];

    int bid = blockIdx.x;
    int n = bid / 100;
    int p0 = (bid % 100) * 64;
    int tid = threadIdx.x;
    int lane = tid & 63;
    int q = tid >> 6;                     // wave id 0..3
    int t = lane;                         // token row (phase 1)
    int p = p0 + t;
    int iatt = ((p / 80) >> 2) * 20 + ((p % 80) >> 2);

    // ---- phase 1 pass 1: x = residual + att -> raw bf16 into xt, stats in regs.
    const float* fbase = feat + ((size_t)(n * 256 + q * 64)) * 6400 + p;
    const float* rrow = r + ((size_t)(n * 400 + iatt)) * 256 + q * 64;
    float s1 = 0.f, s2 = 0.f;
#pragma unroll
    for (int jj = 0; jj < 8; ++jj) {
        union { bf8_t v; unsigned short u[8]; } pk;
#pragma unroll
        for (int e = 0; e < 8; ++e) {
            int j = jj * 8 + e;
            float v = fbase[(size_t)j * 6400] + rrow[j];
            s1 += v;
            s2 += v * v;
            pk.u[e] = f2bf(v);
        }
        int byte = t * 512 + ((q * 128 + jj * 16) ^ ((t & 7) << 4));
        *reinterpret_cast<bf8_t*>(reinterpret_cast<char*>(xt) + byte) = pk.v;
    }
    psum[q][t] = s1;
    psq[q][t] = s2;
    light_barrier();
    if (tid < 64) {
        float a = psum[0][tid] + psum[1][tid] + psum[2][tid] + psum[3][tid];
        float b = psq[0][tid] + psq[1][tid] + psq[2][tid] + psq[3][tid];
        float mu = a * (1.f / 256.f);
        float var = b * (1.f / 256.f) - mu * mu;
        stat[0][tid] = mu;
        stat[1][tid] = rsqrtf(var + LN_EPS);
    }
    light_barrier();
    // ---- phase 1 pass 2: normalize xt in place.
    float mu = stat[0][t], rs = stat[1][t];
#pragma unroll
    for (int jj = 0; jj < 8; ++jj) {
        int byte = t * 512 + ((q * 128 + jj * 16) ^ ((t & 7) << 4));
        union { bf8_t v; unsigned short u[8]; } pk;
        pk.v = *reinterpret_cast<const bf8_t*>(reinterpret_cast<const char*>(xt) + byte);
#pragma unroll
        for (int e = 0; e < 8; ++e) {
            int c = q * 64 + jj * 8 + e;
            float v = bf2f(pk.u[e]);
            pk.u[e] = f2bf((v - mu) * rs * ln1g[c] + ln1b[c]);
        }
        *reinterpret_cast<bf8_t*>(reinterpret_cast<char*>(xt) + byte) = pk.v;
    }
    light_barrier();

    // ---- MFMA phase ----
    int lm = lane & 15, lk = lane >> 4;
    const char* xtb = reinterpret_cast<const char*>(xt);

    f4_t oacc[16];   // [hh*8 + m*4 + cl]
#pragma unroll
    for (int i = 0; i < 16; ++i) oacc[i] = (f4_t){0.f, 0.f, 0.f, 0.f};

    // prologue: prefetch fc=0's kbh=0 W1 batch
    bf8_t bfr0[8];
    {
        const bf8_t* w1p = W1f + ((size_t)(0 * 8 + 2 * q) * 8) * 64 + lane;
#pragma unroll
        for (int kb = 0; kb < 4; ++kb) {
            bfr0[kb * 2 + 0] = w1p[(0 * 8 + kb) * 64];
            bfr0[kb * 2 + 1] = w1p[(1 * 8 + kb) * 64];
        }
    }

    for (int fc = 0; fc < 8; ++fc) {
        const bf8_t* w1p = W1f + ((size_t)(fc * 8 + 2 * q) * 8) * 64 + lane;
        f4_t hacc[8];   // [hh*4 + m*2 + ftl]
#pragma unroll
        for (int i = 0; i < 8; ++i) hacc[i] = (f4_t){0.f, 0.f, 0.f, 0.f};
#pragma unroll
        for (int kbh = 0; kbh < 2; ++kbh) {
            bf8_t bfr[8];
            if (kbh == 0) {
#pragma unroll
                for (int i = 0; i < 8; ++i) bfr[i] = bfr0[i];
            } else {
#pragma unroll
                for (int kb = 0; kb < 4; ++kb) {
                    bfr[kb * 2 + 0] = w1p[(0 * 8 + 4 + kb) * 64];
                    bfr[kb * 2 + 1] = w1p[(1 * 8 + 4 + kb) * 64];
                }
            }
#pragma unroll
            for (int kb = 0; kb < 4; ++kb) {
                int kbb = kbh * 4 + kb;
#pragma unroll
                for (int hh = 0; hh < 2; ++hh) {
#pragma unroll
                    for (int m = 0; m < 2; ++m) {
                        int row = hh * 32 + m * 16 + lm;
                        bf8_t a = *reinterpret_cast<const bf8_t*>(
                            xtb + row * 512 + ((kbb * 64 + lk * 16) ^ ((row & 7) << 4)));
                        hacc[hh * 4 + m * 2 + 0] = __builtin_amdgcn_mfma_f32_16x16x32_bf16(a, bfr[kb * 2 + 0], hacc[hh * 4 + m * 2 + 0], 0, 0, 0);
                        hacc[hh * 4 + m * 2 + 1] = __builtin_amdgcn_mfma_f32_16x16x32_bf16(a, bfr[kb * 2 + 1], hacc[hh * 4 + m * 2 + 1], 0, 0, 0);
                    }
                }
            }
        }
        // issue W2 B-frags for c-tiles {4q,4q+1}; latency hides under the GELUs
        const bf8_t* w2p = W2f + ((size_t)(q * 4) * 32 + fc * 4) * 64 + lane;
        bf8_t b2rA[8];
#pragma unroll
        for (int kb = 0; kb < 4; ++kb) {
            b2rA[kb * 2 + 0] = w2p[(0 * 32 + kb) * 64];
            b2rA[kb * 2 + 1] = w2p[(1 * 32 + kb) * 64];
        }
        // GELU both halves -> ht[0], ht[1] (wave q owns cols (2q..2q+1)*16)
#pragma unroll
        for (int hh = 0; hh < 2; ++hh) {
            char* htc = reinterpret_cast<char*>(ht[hh]);
#pragma unroll
            for (int ftl = 0; ftl < 2; ++ftl) {
                int fl = (2 * q + ftl) * 16 + lm;
                float bias = b1[fc * 128 + fl];
#pragma unroll
                for (int m = 0; m < 2; ++m) {
#pragma unroll
                    for (int j = 0; j < 4; ++j) {
                        int row = m * 16 + lk * 4 + j;   // half-local 0..31
                        float gv = gelu_f(hacc[hh * 4 + m * 2 + ftl][j] + bias);
                        *reinterpret_cast<unsigned short*>(
                            htc + row * 256 + ((fl * 2) ^ ((row & 7) << 4))) = f2bf(gv);
                    }
                }
            }
        }
        light_barrier();   // both ht buffers written
        // second W2 batch + NEXT fc's kbh=0 W1 batch (hide under G2 MFMAs)
        bf8_t b2rB[8];
#pragma unroll
        for (int kb = 0; kb < 4; ++kb) {
            b2rB[kb * 2 + 0] = w2p[(2 * 32 + kb) * 64];
            b2rB[kb * 2 + 1] = w2p[(3 * 32 + kb) * 64];
        }
        if (fc < 7) {
            const bf8_t* w1n = W1f + ((size_t)((fc + 1) * 8 + 2 * q) * 8) * 64 + lane;
#pragma unroll
            for (int kb = 0; kb < 4; ++kb) {
                bfr0[kb * 2 + 0] = w1n[(0 * 8 + kb) * 64];
                bfr0[kb * 2 + 1] = w1n[(1 * 8 + kb) * 64];
            }
        }
        // GEMM2 both halves; B-frags shared
#pragma unroll
        for (int hh = 0; hh < 2; ++hh) {
            const char* htc = reinterpret_cast<const char*>(ht[hh]);
#pragma unroll
            for (int kb = 0; kb < 4; ++kb) {
#pragma unroll
                for (int m = 0; m < 2; ++m) {
                    int row = m * 16 + lm;
                    bf8_t a = *reinterpret_cast<const bf8_t*>(
                        htc + row * 256 + ((kb * 64 + lk * 16) ^ ((row & 7) << 4)));
                    oacc[hh * 8 + m * 4 + 0] = __builtin_amdgcn_mfma_f32_16x16x32_bf16(a, b2rA[kb * 2 + 0], oacc[hh * 8 + m * 4 + 0], 0, 0, 0);
                    oacc[hh * 8 + m * 4 + 1] = __builtin_amdgcn_mfma_f32_16x16x32_bf16(a, b2rA[kb * 2 + 1], oacc[hh * 8 + m * 4 + 1], 0, 0, 0);
                    oacc[hh * 8 + m * 4 + 2] = __builtin_amdgcn_mfma_f32_16x16x32_bf16(a, b2rB[kb * 2 + 0], oacc[hh * 8 + m * 4 + 2], 0, 0, 0);
                    oacc[hh * 8 + m * 4 + 3] = __builtin_amdgcn_mfma_f32_16x16x32_bf16(a, b2rB[kb * 2 + 1], oacc[hh * 8 + m * 4 + 3], 0, 0, 0);
                }
            }
        }
        light_barrier();   // all ht reads done before next fc's GELU writes
    }

    // ---- epilogue: + b2 + residual2, LN2, store. Wave q owns c (4q..4q+3)*16.
    float b2l[4];
#pragma unroll
    for (int cl = 0; cl < 4; ++cl) b2l[cl] = b2[(q * 4 + cl) * 16 + lm];
#pragma unroll
    for (int hh = 0; hh < 2; ++hh) {
#pragma unroll
        for (int m = 0; m < 2; ++m) {
#pragma unroll
            for (int j = 0; j < 4; ++j) {
                int row = hh * 32 + m * 16 + lk * 4 + j;
                float s = 0.f, ss = 0.f;
#pragma unroll
                for (int cl = 0; cl < 4; ++cl) {
                    int c = (q * 4 + cl) * 16 + lm;
                    float res = bf2f(*reinterpret_cast<const unsigned short*>(
                        xtb + row * 512 + ((c * 2) ^ ((row & 7) << 4))));
                    float v = oacc[hh * 8 + m * 4 + cl][j] + b2l[cl] + res;
                    oacc[hh * 8 + m * 4 + cl][j] = v;
                    s += v;
                    ss += v * v;
                }
#pragma unroll
                for (int d = 1; d < 16; d <<= 1) {
                    s += __shfl_xor(s, d, 64);
                    ss += __shfl_xor(ss, d, 64);
                }
                if (lm == 0) { psum[q][row] = s; psq[q][row] = ss; }
            }
        }
    }
    light_barrier();
    if (tid < 64) {
        float a = psum[0][tid] + psum[1][tid] + psum[2][tid] + psum[3][tid];
        float b = psq[0][tid] + psq[1][tid] + psq[2][tid] + psq[3][tid];
        float mu2 = a * (1.f / 256.f);
        float var = b * (1.f / 256.f) - mu2 * mu2;
        stat[0][tid] = mu2;
        stat[1][tid] = rsqrtf(var + LN_EPS);
    }
    light_barrier();
    float g2[4], be2[4];
#pragma unroll
    for (int cl = 0; cl < 4; ++cl) {
        int c = (q * 4 + cl) * 16 + lm;
        g2[cl] = ln2g[c];
        be2[cl] = ln2b[c];
    }
    float* obase = out + ((size_t)(n * 6400 + p0)) * 256;
#pragma unroll
    for (int hh = 0; hh < 2; ++hh) {
#pragma unroll
        for (int m = 0; m < 2; ++m) {
#pragma unroll
            for (int j = 0; j < 4; ++j) {
                int row = hh * 32 + m * 16 + lk * 4 + j;
                float mu2 = stat[0][row], r2 = stat[1][row];
#pragma unroll
                for (int cl = 0; cl < 4; ++cl) {
                    int c = (q * 4 + cl) * 16 + lm;
                    obase[(size_t)row * 256 + c] =
                        (oacc[hh * 8 + m * 4 + cl][j] - mu2) * r2 * g2[cl] + be2[cl];
                }
            }
        }
    }
}

extern "C" void kernel_launch(void* const* d_in, const int* in_sizes, int n_in,
                              void* d_out, int out_size, void* d_ws, size_t ws_size,
                              hipStream_t stream) {
    const float* weight = (const float*)d_in[0];   // [8,400,400]
    const float* feature = (const float*)d_in[1];  // [8,256,80,80]
    const float* ln1g = (const float*)d_in[2];
    const float* ln1b = (const float*)d_in[3];
    const float* W1 = (const float*)d_in[4];       // [1024,256]
    const float* b1 = (const float*)d_in[5];
    const float* W2 = (const float*)d_in[6];       // [256,1024]
    const float* b2 = (const float*)d_in[7];
    const float* ln2g = (const float*)d_in[8];
    const float* ln2b = (const float*)d_in[9];
    float* outp = (float*)d_out;

    unsigned short* fsb = (unsigned short*)d_ws;      // 819200 bf16 (1.6 MB)
    float* rbuf = (float*)(fsb + 819200);             // 819200 f32
    bf8_t* W1f = (bf8_t*)(rbuf + 819200);             // 32768 frags (512 KB)
    bf8_t* W2f = W1f + 32768;                         // 32768 frags (512 KB)

    pool_cvt_kernel<<<2304, 256, 0, stream>>>(feature, fsb, W1, W2, W1f, W2f);
    att_kernel<<<400, 256, 0, stream>>>(weight, fsb, rbuf);
    main_kernel<<<800, 256, 0, stream>>>(feature, rbuf, ln1g, ln1b, W1f, b1,
                                         W2f, b2, ln2g, ln2b, outp);
}